// Round 13
// baseline (113.826 us; speedup 1.0000x reference)
//
#include <hip/hip_runtime.h>

#define BB 32
#define MM 512
#define SS 10
#define VV 32000
#define DD 128
#define HOPS 3
#define BM (BB * MM)
#define NCHUNK 32          // chunks per b -> grid 32*32 = 1024 blocks for K1/K2
#define CHM (MM / NCHUNK)  // 16 m per chunk -> 4 m per wave
#define PSTRIDE 132        // partial row: 128 num + 1 den + pad
#define UT1 ((size_t)VV * DD / 8)     // uint4 cvt units, single table (C1)
#define UTP ((size_t)VV * 32)         // uint4 cvt units, interleaved pair (C2,C3)

// bf16 helpers (RN pack; exact unpack)
__device__ __forceinline__ unsigned bfrn(float f) {
    unsigned u = __float_as_uint(f);
    return (u + 0x7FFFu + ((u >> 16) & 1u)) >> 16;
}
__device__ __forceinline__ unsigned pk(float a, float b) { return bfrn(a) | (bfrn(b) << 16); }
__device__ __forceinline__ float bflo(unsigned q) { return __uint_as_float(q << 16); }
__device__ __forceinline__ float bfhi(unsigned q) { return __uint_as_float(q & 0xFFFF0000u); }

// single-table cvt: unit g = 8 consecutive f32 -> uint4 of 8 bf16
__device__ __forceinline__ void cvt_unit(const float* __restrict__ C,
                                         unsigned* __restrict__ Cb, size_t g) {
    const float4 f0 = ((const float4*)C)[g * 2];
    const float4 f1 = ((const float4*)C)[g * 2 + 1];
    uint4 o;
    o.x = pk(f0.x, f0.y);
    o.y = pk(f0.z, f0.w);
    o.z = pk(f1.x, f1.y);
    o.w = pk(f1.z, f1.w);
    ((uint4*)Cb)[g] = o;
}

// pair cvt: row v = 128 words; uint2 word-pair for lane l = {tabA d=2l..., tabB d=2l...}
__device__ __forceinline__ void cvt_pair_unit(const float* __restrict__ CA,
                                              const float* __restrict__ CB,
                                              unsigned* __restrict__ dst, size_t g) {
    const size_t v = g >> 5, j = g & 31;
    const float4 a = ((const float4*)CA)[v * 32 + j];
    const float4 b = ((const float4*)CB)[v * 32 + j];
    uint4 o;
    o.x = pk(a.x, a.y);
    o.y = pk(b.x, b.y);
    o.z = pk(a.z, a.w);
    o.w = pk(b.z, b.w);
    ((uint4*)dst)[v * 32 + j] = o;
}

// ====================== PRIMARY PATH (4 kernels) ======================

// K0: cu0[v][b] = dot(C0[v,:], hidden[b,:])  (dense GEMV, f32 exact)
// lane l -> (b = l>>1, half = l&1); u-slice in 64 VGPRs; 1 shfl per output.
// Tail: cvt C1 -> Cb1 (single-table bf16).
__global__ __launch_bounds__(256) void gemv0_k(const float* __restrict__ C0,
                                               const float* __restrict__ hidden,
                                               float* __restrict__ cu0,
                                               const float* __restrict__ Cmat,
                                               unsigned* __restrict__ Cb1) {
    const int tid = threadIdx.x;
    const int w = tid >> 6, lane = tid & 63;
    const int gw = blockIdx.x * 4 + w;          // global wave id, 0..2047
    const int b = lane >> 1, half = lane & 1;

    float4 ur[16];
    const float4* h4 = (const float4*)hidden;
#pragma unroll
    for (int i = 0; i < 16; ++i) ur[i] = h4[b * 32 + half * 16 + i];

#pragma unroll
    for (int r = 0; r < 16; ++r) {
        const int v = gw * 16 + r;
        if (v < VV) {
            const float4* Crow = (const float4*)(C0 + (size_t)v * DD) + half * 16;
            float p = 0.f;
#pragma unroll
            for (int i = 0; i < 16; ++i) {
                const float4 c = Crow[i];
                p += c.x * ur[i].x + c.y * ur[i].y + c.z * ur[i].z + c.w * ur[i].w;
            }
            p += __shfl_xor(p, 1, 64);
            if (half == 0) cu0[(size_t)v * BB + b] = p;
        }
    }

    // cvt C1 tail: 512 blocks x 256 thr x 4 units = 524288 >= UT1
    const size_t t0 = ((size_t)blockIdx.x * 256 + tid) * 4;
#pragma unroll
    for (int i = 0; i < 4; ++i) {
        const size_t g = t0 + i;
        if (g < UT1) cvt_unit(Cmat + (size_t)VV * DD, Cb1, g);
    }
}

__device__ __forceinline__ void write_partial(const int b, const int c,
                                              const int w, const int lane,
                                              float nx, float ny, float den,
                                              float* __restrict__ pout,
                                              float (*sx)[64], float (*sy)[64],
                                              float* sd) {
    sx[w][lane] = nx; sy[w][lane] = ny;
    if (lane == 0) sd[w] = den;
    __syncthreads();
    if (w == 0) {
        const float ox = sx[0][lane] + sx[1][lane] + sx[2][lane] + sx[3][lane];
        const float oy = sy[0][lane] + sy[1][lane] + sy[2][lane] + sy[3][lane];
        float* prow = pout + ((size_t)b * NCHUNK + c) * PSTRIDE;
        ((float2*)prow)[lane] = make_float2(ox, oy);
        if (lane == 0) prow[DD] = sd[0] + sd[1] + sd[2] + sd[3];
    }
}

// K1 (hop0): l0 from cu0 (broadcast scalar reads, exact f32); gather Cb1 rows ->
// E1 (bf16-packed) + weighted acc -> P0.  Tail: cvt (C2,C3) -> Cb23 pair.
__global__ __launch_bounds__(256) void hop0_k(const int* __restrict__ story,
                                              const float* __restrict__ cu0,
                                              const unsigned* __restrict__ Cb1,
                                              unsigned* __restrict__ E1,
                                              float* __restrict__ P0,
                                              const float* __restrict__ Cmat,
                                              unsigned* __restrict__ Cb23) {
    const int b = blockIdx.y, c = blockIdx.x;
    const int tid = threadIdx.x;
    const int w = tid >> 6, lane = tid & 63;
    __shared__ float sx[4][64], sy[4][64];
    __shared__ float sd[4];

    float nx = 0.f, ny = 0.f, den = 0.f;
#pragma unroll
    for (int k = 0; k < CHM / 4; ++k) {
        const int m = c * CHM + k * 4 + w;
        const int bm = b * MM + m;
        int tok[SS];
        const int* st = story + (size_t)bm * SS;
#pragma unroll
        for (int s = 0; s < SS; ++s) tok[s] = st[s];

        float l = 0.f;
#pragma unroll
        for (int s = 0; s < SS; ++s) l += cu0[(size_t)tok[s] * BB + b];
        const float e = expf(l);

        float rx = 0.f, ry = 0.f;
#pragma unroll
        for (int s = 0; s < SS; ++s) {
            const unsigned q = Cb1[(size_t)tok[s] * 64 + lane];
            rx += bflo(q); ry += bfhi(q);
        }
        E1[(size_t)bm * 64 + lane] = pk(rx, ry);
        nx += e * rx; ny += e * ry; den += e;
    }
    write_partial(b, c, w, lane, nx, ny, den, P0, sx, sy, sd);

    // cvt pair tail: 1024 blocks x 256 thr x 4 units = 1048576 >= UTP
    const size_t t0 = (((size_t)blockIdx.y * gridDim.x + blockIdx.x) * 256 + tid) * 4;
#pragma unroll
    for (int i = 0; i < 4; ++i) {
        const size_t g = t0 + i;
        if (g < UTP)
            cvt_pair_unit(Cmat + (size_t)2 * VV * DD, Cmat + (size_t)3 * VV * DD,
                          Cb23, g);
    }
}

// K2 (hop1): logit from E1 (bf16); gather Cb23 pair -> E23 (bf16 pair) + acc(C2) -> P1.
// u1 = hidden + red(P0); c==0 materializes u1.
__global__ __launch_bounds__(256) void hop1_k(const int* __restrict__ story,
                                              const unsigned* __restrict__ Cb23,
                                              const unsigned* __restrict__ E1,
                                              const float* __restrict__ hidden,
                                              const float* __restrict__ P0,
                                              float* __restrict__ u1,
                                              unsigned* __restrict__ E23,
                                              float* __restrict__ P1) {
    const int b = blockIdx.y, c = blockIdx.x;
    const int tid = threadIdx.x;
    const int w = tid >> 6, lane = tid & 63;
    __shared__ float su[DD];
    __shared__ float sx[4][64], sy[4][64];
    __shared__ float sd[4];

    if (tid < DD) {
        float num = 0.f, dsum = 0.f;
        for (int cc = 0; cc < NCHUNK; ++cc) {
            const float* p = P0 + ((size_t)b * NCHUNK + cc) * PSTRIDE;
            num += p[tid];
            dsum += p[DD];
        }
        const float v = hidden[b * DD + tid] + num / dsum;
        if (c == 0) u1[b * DD + tid] = v;
        su[tid] = v;
    }
    __syncthreads();
    const float2 uv = ((const float2*)su)[lane];

    float nx = 0.f, ny = 0.f, den = 0.f;
#pragma unroll
    for (int k = 0; k < CHM / 4; ++k) {
        const int m = c * CHM + k * 4 + w;
        const int bm = b * MM + m;
        int tok[SS];
        const int* st = story + (size_t)bm * SS;
#pragma unroll
        for (int s = 0; s < SS; ++s) tok[s] = st[s];

        const unsigned eq = E1[(size_t)bm * 64 + lane];
        float l = bflo(eq) * uv.x + bfhi(eq) * uv.y;
#pragma unroll
        for (int off = 32; off; off >>= 1) l += __shfl_xor(l, off, 64);
        const float e = expf(l);

        float r2x = 0.f, r2y = 0.f, r3x = 0.f, r3y = 0.f;
#pragma unroll
        for (int s = 0; s < SS; ++s) {
            const uint2 q = ((const uint2*)Cb23)[(size_t)tok[s] * 64 + lane];
            r2x += bflo(q.x); r2y += bfhi(q.x);
            r3x += bflo(q.y); r3y += bfhi(q.y);
        }
        ((uint2*)E23)[(size_t)bm * 64 + lane] = make_uint2(pk(r2x, r2y), pk(r3x, r3y));
        nx += e * r2x; ny += e * r2y; den += e;
    }
    write_partial(b, c, w, lane, nx, ny, den, P1, sx, sy, sd);
}

// K3 (hop2 + final): one block per b, 1024 threads. Fully dense from E23 pair.
// u2 = u1 + red(P1); final logit from E2-half; output from E3-half; uout direct.
__global__ __launch_bounds__(1024) void hop2_final(const unsigned* __restrict__ E23,
                                                   const float* __restrict__ u1,
                                                   const float* __restrict__ P1,
                                                   float* __restrict__ logit,
                                                   float* __restrict__ uout) {
    const int b = blockIdx.x;
    const int tid = threadIdx.x;
    const int w = tid >> 6, lane = tid & 63;
    __shared__ float su[DD];
    __shared__ float sx[16][64], sy[16][64];
    __shared__ float sd[16];

    if (tid < DD) {
        float num = 0.f, dsum = 0.f;
        for (int cc = 0; cc < NCHUNK; ++cc) {
            const float* p = P1 + ((size_t)b * NCHUNK + cc) * PSTRIDE;
            num += p[tid];
            dsum += p[DD];
        }
        su[tid] = u1[b * DD + tid] + num / dsum;
    }
    __syncthreads();
    const float2 uv = ((const float2*)su)[lane];

    float nx = 0.f, ny = 0.f, den = 0.f;
#pragma unroll 4
    for (int m = w * 32; m < w * 32 + 32; ++m) {
        const int bm = b * MM + m;
        const uint2 q = ((const uint2*)E23)[(size_t)bm * 64 + lane];
        float l = bflo(q.x) * uv.x + bfhi(q.x) * uv.y;
#pragma unroll
        for (int off = 32; off; off >>= 1) l += __shfl_xor(l, off, 64);
        if (lane == 0) logit[bm] = l;
        const float e = expf(l);
        nx += e * bflo(q.y); ny += e * bfhi(q.y); den += e;
    }

    sx[w][lane] = nx; sy[w][lane] = ny;
    if (lane == 0) sd[w] = den;
    __syncthreads();
    if (w == 0) {
        float ox = 0.f, oy = 0.f, od = 0.f;
#pragma unroll
        for (int i = 0; i < 16; ++i) { ox += sx[i][lane]; oy += sy[i][lane]; od += sd[i]; }
        const float2 u2 = ((const float2*)su)[lane];
        ((float2*)(uout + b * DD))[lane] = make_float2(u2.x + ox / od, u2.y + oy / od);
    }
}

// ====================== FALLBACK PATH (round-1, known-good) ======================
__global__ __launch_bounds__(256) void init_u(const float* __restrict__ hidden,
                                              float* __restrict__ u) {
    int i = blockIdx.x * 256 + threadIdx.x;
    if (i < BB * DD) u[i] = hidden[i];
}

__global__ __launch_bounds__(256) void logit_kernel(const int* __restrict__ story,
                                                    const float* __restrict__ Ch,
                                                    const float* __restrict__ u,
                                                    float* __restrict__ logit) {
    int wid = (blockIdx.x * 256 + threadIdx.x) >> 6;
    int lane = threadIdx.x & 63;
    if (wid >= BB * MM) return;
    int b = wid >> 9;
    const int* st = story + (size_t)wid * SS;
    int tok[SS];
#pragma unroll
    for (int s = 0; s < SS; ++s) tok[s] = st[s];
    float ax = 0.f, ay = 0.f;
#pragma unroll
    for (int s = 0; s < SS; ++s) {
        const float2 v = ((const float2*)(Ch + (size_t)tok[s] * DD))[lane];
        ax += v.x; ay += v.y;
    }
    const float2 uv = ((const float2*)(u + b * DD))[lane];
    float p = ax * uv.x + ay * uv.y;
#pragma unroll
    for (int off = 32; off; off >>= 1) p += __shfl_down(p, off, 64);
    if (lane == 0) logit[wid] = p;
}

__global__ __launch_bounds__(256) void softmax_kernel(const float* __restrict__ logit,
                                                      float* __restrict__ prob) {
    int b = blockIdx.x;
    int t = threadIdx.x;
    __shared__ float red[8];
    float l0 = logit[b * MM + t];
    float l1 = logit[b * MM + 256 + t];
    float mx = fmaxf(l0, l1);
#pragma unroll
    for (int off = 32; off; off >>= 1) mx = fmaxf(mx, __shfl_xor(mx, off, 64));
    if ((t & 63) == 0) red[t >> 6] = mx;
    __syncthreads();
    mx = fmaxf(fmaxf(red[0], red[1]), fmaxf(red[2], red[3]));
    float e0 = expf(l0 - mx), e1 = expf(l1 - mx);
    float s = e0 + e1;
#pragma unroll
    for (int off = 32; off; off >>= 1) s += __shfl_xor(s, off, 64);
    if ((t & 63) == 0) red[4 + (t >> 6)] = s;
    __syncthreads();
    s = red[4] + red[5] + red[6] + red[7];
    float inv = 1.0f / s;
    prob[b * MM + t] = e0 * inv;
    prob[b * MM + 256 + t] = e1 * inv;
}

__global__ __launch_bounds__(256) void partial_kernel(const int* __restrict__ story,
                                                      const float* __restrict__ Ch1,
                                                      const float* __restrict__ prob,
                                                      float* __restrict__ partial,
                                                      int chunk) {
    int b = blockIdx.y, c = blockIdx.x;
    int w = threadIdx.x >> 6, lane = threadIdx.x & 63;
    int m0 = c * chunk;
    float ax = 0.f, ay = 0.f;
    for (int m = m0 + w; m < m0 + chunk; m += 4) {
        float pw = prob[b * MM + m];
        const int* st = story + (size_t)(b * MM + m) * SS;
        int tok[SS];
#pragma unroll
        for (int s = 0; s < SS; ++s) tok[s] = st[s];
        float sx = 0.f, sy = 0.f;
#pragma unroll
        for (int s = 0; s < SS; ++s) {
            const float2 v = ((const float2*)(Ch1 + (size_t)tok[s] * DD))[lane];
            sx += v.x; sy += v.y;
        }
        ax += pw * sx; ay += pw * sy;
    }
    __shared__ float redx[4][64];
    __shared__ float redy[4][64];
    redx[w][lane] = ax;
    redy[w][lane] = ay;
    __syncthreads();
    if (w == 0) {
        float ox = redx[0][lane] + redx[1][lane] + redx[2][lane] + redx[3][lane];
        float oy = redy[0][lane] + redy[1][lane] + redy[2][lane] + redy[3][lane];
        float2* dst = (float2*)(partial + ((size_t)b * gridDim.x + c) * DD);
        dst[lane] = make_float2(ox, oy);
    }
}

__global__ __launch_bounds__(256) void update_kernel(const float* __restrict__ partial,
                                                     float* __restrict__ u, int NC) {
    int i = blockIdx.x * 256 + threadIdx.x;
    if (i >= BB * DD) return;
    int b = i >> 7, d = i & 127;
    float s = 0.f;
    for (int c = 0; c < NC; ++c) s += partial[((size_t)b * NC + c) * DD + d];
    u[i] += s;
}

extern "C" void kernel_launch(void* const* d_in, const int* in_sizes, int n_in,
                              void* d_out, int out_size, void* d_ws, size_t ws_size,
                              hipStream_t stream) {
    const int*   story  = (const int*)d_in[0];
    const float* hidden = (const float*)d_in[1];
    const float* Cmat   = (const float*)d_in[2];

    float* out   = (float*)d_out;
    float* logit = out;              // final prob_logit [B,M]
    float* uout  = out + BB * MM;    // final u [B,D]

    // ws words: cu0 | Cb1 | Cb23 | E1 | E23 | P0 P1 | u1
    const size_t szCU  = (size_t)VV * BB;        // 1.024M f32
    const size_t szCb1 = (size_t)VV * 64;        // 2.048M words
    const size_t szCbp = (size_t)VV * 128;       // 4.096M words
    const size_t szE1  = (size_t)BM * 64;        // 1.048M words
    const size_t szE23 = (size_t)BM * 128;       // 2.097M words
    const size_t szP   = (size_t)BB * NCHUNK * PSTRIDE;
    const size_t need  = (szCU + szCb1 + szCbp + szE1 + szE23 + 2 * szP + BB * DD)
                         * sizeof(float);

    if (ws_size >= need) {
        float*    cu0  = (float*)d_ws;
        unsigned* Cb1  = (unsigned*)d_ws + szCU;
        unsigned* Cb23 = Cb1 + szCb1;
        unsigned* E1   = Cb23 + szCbp;
        unsigned* E23  = E1 + szE1;
        float*    P0   = (float*)(E23 + szE23);
        float*    P1   = P0 + szP;
        float*    u1   = P1 + szP;

        gemv0_k<<<512, 256, 0, stream>>>(Cmat, hidden, cu0, Cmat, Cb1);
        hop0_k<<<dim3(NCHUNK, BB), 256, 0, stream>>>(story, cu0, Cb1, E1, P0,
                                                     Cmat, Cb23);
        hop1_k<<<dim3(NCHUNK, BB), 256, 0, stream>>>(story, Cb23, E1, hidden,
                                                     P0, u1, E23, P1);
        hop2_final<<<BB, 1024, 0, stream>>>(E23, u1, P1, logit, uout);
    } else {
        float* prob = (float*)d_ws;
        int NC = 32;
        while (NC > 1 && (size_t)(BB * MM + BB * NC * DD) * 4 > ws_size) NC >>= 1;
        float* partial = prob + BB * MM;
        int chunk = MM / NC;

        init_u<<<(BB * DD + 255) / 256, 256, 0, stream>>>(hidden, uout);
        for (int h = 0; h < HOPS; ++h) {
            const float* Ca = Cmat + (size_t)h * VV * DD;
            const float* Cc = Cmat + (size_t)(h + 1) * VV * DD;
            logit_kernel<<<(BB * MM) / 4, 256, 0, stream>>>(story, Ca, uout, logit);
            softmax_kernel<<<BB, 256, 0, stream>>>(logit, prob);
            partial_kernel<<<dim3(NC, BB), 256, 0, stream>>>(story, Cc, prob, partial, chunk);
            update_kernel<<<(BB * DD + 255) / 256, 256, 0, stream>>>(partial, uout, NC);
        }
    }
}

// Round 14
// 92.867 us; speedup vs baseline: 1.2257x; 1.2257x over previous
//
#include <hip/hip_runtime.h>

#define BB 32
#define MM 512
#define SS 10
#define VV 32000
#define DD 128
#define HOPS 3
#define BM (BB * MM)
#define NCHUNK 32          // chunks per b -> grid 32*32 = 1024 blocks for K1/K2
#define CHM (MM / NCHUNK)  // 16 m per chunk -> 4 m per wave
#define PSTRIDE 132        // partial row: 128 num + 1 den + pad
#define UT1 ((size_t)VV * DD / 8)     // uint4 cvt units, single table (C1)
#define UTP ((size_t)VV * 32)         // uint4 cvt units, interleaved pair (C2,C3)

// bf16 helpers (RN pack; exact unpack)
__device__ __forceinline__ unsigned bfrn(float f) {
    unsigned u = __float_as_uint(f);
    return (u + 0x7FFFu + ((u >> 16) & 1u)) >> 16;
}
__device__ __forceinline__ unsigned pk(float a, float b) { return bfrn(a) | (bfrn(b) << 16); }
__device__ __forceinline__ float bflo(unsigned q) { return __uint_as_float(q << 16); }
__device__ __forceinline__ float bfhi(unsigned q) { return __uint_as_float(q & 0xFFFF0000u); }

// single-table cvt: unit g = 8 consecutive f32 -> uint4 of 8 bf16
__device__ __forceinline__ void cvt_unit(const float* __restrict__ C,
                                         unsigned* __restrict__ Cb, size_t g) {
    const float4 f0 = ((const float4*)C)[g * 2];
    const float4 f1 = ((const float4*)C)[g * 2 + 1];
    uint4 o;
    o.x = pk(f0.x, f0.y);
    o.y = pk(f0.z, f0.w);
    o.z = pk(f1.x, f1.y);
    o.w = pk(f1.z, f1.w);
    ((uint4*)Cb)[g] = o;
}

// pair cvt: row v = 128 words; uint2 word-pair for lane l = {tabA d=2l..., tabB d=2l...}
__device__ __forceinline__ void cvt_pair_unit(const float* __restrict__ CA,
                                              const float* __restrict__ CB,
                                              unsigned* __restrict__ dst, size_t g) {
    const size_t v = g >> 5, j = g & 31;
    const float4 a = ((const float4*)CA)[v * 32 + j];
    const float4 b = ((const float4*)CB)[v * 32 + j];
    uint4 o;
    o.x = pk(a.x, a.y);
    o.y = pk(b.x, b.y);
    o.z = pk(a.z, a.w);
    o.w = pk(b.z, b.w);
    ((uint4*)dst)[v * 32 + j] = o;
}

// ====================== PRIMARY PATH (4 kernels) ======================

// K0: cu0[v][b] = dot(C0[v,:], hidden[b,:])  (dense GEMV, f32 exact).
// thread t -> (row v = v0 + t>>2, quarter q = t&3): per-lane-distinct coalesced
// C reads (32 floats in VGPRs), u from LDS (4-way broadcast), quad shfl butterfly,
// LDS-staged coalesced store.  Tail: cvt C1 -> Cb1 (single-table bf16).
__global__ __launch_bounds__(256) void gemv0_k(const float* __restrict__ C0,
                                               const float* __restrict__ hidden,
                                               float* __restrict__ cu0,
                                               const float* __restrict__ Cmat,
                                               unsigned* __restrict__ Cb1) {
    __shared__ float su[BB * DD];     // 16 KB
    __shared__ float scu[64 * BB];    // 8 KB
    const int tid = threadIdx.x;
    const int v0 = blockIdx.x * 64;

    // stage u (coalesced)
    {
        const float4* h4 = (const float4*)hidden;
        float4* s4 = (float4*)su;
        for (int i = tid; i < BB * DD / 4; i += 256) s4[i] = h4[i];
    }
    __syncthreads();

    const int vl = tid >> 2;          // local row 0..63
    const int q  = tid & 3;           // row quarter
    const int v  = v0 + vl;

    // this thread's 32 floats of row v (quarter q): lane-distinct, line-dense over i
    float4 c4[8];
    const float4* Crow = (const float4*)(C0 + (size_t)v * DD) + q * 8;
#pragma unroll
    for (int i = 0; i < 8; ++i) c4[i] = Crow[i];

    float acc[BB];
    const float4* su4 = (const float4*)su;   // index: b*32 + q*8 + i
#pragma unroll
    for (int b = 0; b < BB; ++b) {
        float p0 = 0.f, p1 = 0.f;
#pragma unroll
        for (int i = 0; i < 8; ++i) {
            const float4 u4 = su4[b * 32 + q * 8 + i];
            p0 += c4[i].x * u4.x + c4[i].y * u4.y;
            p1 += c4[i].z * u4.z + c4[i].w * u4.w;
        }
        acc[b] = p0 + p1;
    }
    // quad butterfly: all 4 quarter-threads end with the full dot
#pragma unroll
    for (int b = 0; b < BB; ++b) {
        acc[b] += __shfl_xor(acc[b], 1, 64);
        acc[b] += __shfl_xor(acc[b], 2, 64);
    }
    if (q == 0) {
#pragma unroll
        for (int b = 0; b < BB; ++b) scu[vl * BB + b] = acc[b];
    }
    __syncthreads();
    // coalesced copy-out: 64 rows x 32 b = 2048 floats
    {
        float2* dst = (float2*)(cu0 + (size_t)v0 * BB);
        const float2* src = (const float2*)scu;
        for (int i = tid; i < 64 * BB / 2; i += 256) dst[i] = src[i];
    }

    // cvt C1 tail: 500 blocks x 256 thr x 4 units = 512000 == UT1
    const size_t t0 = ((size_t)blockIdx.x * 256 + tid) * 4;
#pragma unroll
    for (int i = 0; i < 4; ++i) {
        const size_t g = t0 + i;
        if (g < UT1) cvt_unit(Cmat + (size_t)VV * DD, Cb1, g);
    }
}

__device__ __forceinline__ void write_partial(const int b, const int c,
                                              const int w, const int lane,
                                              float nx, float ny, float den,
                                              float* __restrict__ pout,
                                              float (*sx)[64], float (*sy)[64],
                                              float* sd) {
    sx[w][lane] = nx; sy[w][lane] = ny;
    if (lane == 0) sd[w] = den;
    __syncthreads();
    if (w == 0) {
        const float ox = sx[0][lane] + sx[1][lane] + sx[2][lane] + sx[3][lane];
        const float oy = sy[0][lane] + sy[1][lane] + sy[2][lane] + sy[3][lane];
        float* prow = pout + ((size_t)b * NCHUNK + c) * PSTRIDE;
        ((float2*)prow)[lane] = make_float2(ox, oy);
        if (lane == 0) prow[DD] = sd[0] + sd[1] + sd[2] + sd[3];
    }
}

// K1 (hop0): l0 from cu0 (broadcast scalar reads, exact f32); gather Cb1 rows ->
// E1 (bf16-packed) + weighted acc -> P0.  Tail: cvt (C2,C3) -> Cb23 pair.
__global__ __launch_bounds__(256) void hop0_k(const int* __restrict__ story,
                                              const float* __restrict__ cu0,
                                              const unsigned* __restrict__ Cb1,
                                              unsigned* __restrict__ E1,
                                              float* __restrict__ P0,
                                              const float* __restrict__ Cmat,
                                              unsigned* __restrict__ Cb23) {
    const int b = blockIdx.y, c = blockIdx.x;
    const int tid = threadIdx.x;
    const int w = tid >> 6, lane = tid & 63;
    __shared__ float sx[4][64], sy[4][64];
    __shared__ float sd[4];

    float nx = 0.f, ny = 0.f, den = 0.f;
#pragma unroll
    for (int k = 0; k < CHM / 4; ++k) {
        const int m = c * CHM + k * 4 + w;
        const int bm = b * MM + m;
        int tok[SS];
        const int* st = story + (size_t)bm * SS;
#pragma unroll
        for (int s = 0; s < SS; ++s) tok[s] = st[s];

        float l = 0.f;
#pragma unroll
        for (int s = 0; s < SS; ++s) l += cu0[(size_t)tok[s] * BB + b];
        const float e = expf(l);

        float rx = 0.f, ry = 0.f;
#pragma unroll
        for (int s = 0; s < SS; ++s) {
            const unsigned q = Cb1[(size_t)tok[s] * 64 + lane];
            rx += bflo(q); ry += bfhi(q);
        }
        E1[(size_t)bm * 64 + lane] = pk(rx, ry);
        nx += e * rx; ny += e * ry; den += e;
    }
    write_partial(b, c, w, lane, nx, ny, den, P0, sx, sy, sd);

    // cvt pair tail: 1024 blocks x 256 thr x 4 units = 1048576 >= UTP
    const size_t t0 = (((size_t)blockIdx.y * gridDim.x + blockIdx.x) * 256 + tid) * 4;
#pragma unroll
    for (int i = 0; i < 4; ++i) {
        const size_t g = t0 + i;
        if (g < UTP)
            cvt_pair_unit(Cmat + (size_t)2 * VV * DD, Cmat + (size_t)3 * VV * DD,
                          Cb23, g);
    }
}

// K2 (hop1): logit from E1 (bf16); gather Cb23 pair -> E23 (bf16 pair) + acc(C2) -> P1.
// u1 = hidden + red(P0); c==0 materializes u1.
__global__ __launch_bounds__(256) void hop1_k(const int* __restrict__ story,
                                              const unsigned* __restrict__ Cb23,
                                              const unsigned* __restrict__ E1,
                                              const float* __restrict__ hidden,
                                              const float* __restrict__ P0,
                                              float* __restrict__ u1,
                                              unsigned* __restrict__ E23,
                                              float* __restrict__ P1) {
    const int b = blockIdx.y, c = blockIdx.x;
    const int tid = threadIdx.x;
    const int w = tid >> 6, lane = tid & 63;
    __shared__ float su[DD];
    __shared__ float sx[4][64], sy[4][64];
    __shared__ float sd[4];

    if (tid < DD) {
        float num = 0.f, dsum = 0.f;
        for (int cc = 0; cc < NCHUNK; ++cc) {
            const float* p = P0 + ((size_t)b * NCHUNK + cc) * PSTRIDE;
            num += p[tid];
            dsum += p[DD];
        }
        const float v = hidden[b * DD + tid] + num / dsum;
        if (c == 0) u1[b * DD + tid] = v;
        su[tid] = v;
    }
    __syncthreads();
    const float2 uv = ((const float2*)su)[lane];

    float nx = 0.f, ny = 0.f, den = 0.f;
#pragma unroll
    for (int k = 0; k < CHM / 4; ++k) {
        const int m = c * CHM + k * 4 + w;
        const int bm = b * MM + m;
        int tok[SS];
        const int* st = story + (size_t)bm * SS;
#pragma unroll
        for (int s = 0; s < SS; ++s) tok[s] = st[s];

        const unsigned eq = E1[(size_t)bm * 64 + lane];
        float l = bflo(eq) * uv.x + bfhi(eq) * uv.y;
#pragma unroll
        for (int off = 32; off; off >>= 1) l += __shfl_xor(l, off, 64);
        const float e = expf(l);

        float r2x = 0.f, r2y = 0.f, r3x = 0.f, r3y = 0.f;
#pragma unroll
        for (int s = 0; s < SS; ++s) {
            const uint2 q = ((const uint2*)Cb23)[(size_t)tok[s] * 64 + lane];
            r2x += bflo(q.x); r2y += bfhi(q.x);
            r3x += bflo(q.y); r3y += bfhi(q.y);
        }
        ((uint2*)E23)[(size_t)bm * 64 + lane] = make_uint2(pk(r2x, r2y), pk(r3x, r3y));
        nx += e * r2x; ny += e * r2y; den += e;
    }
    write_partial(b, c, w, lane, nx, ny, den, P1, sx, sy, sd);
}

// K3 (hop2 + final): one block per b, 1024 threads. Fully dense from E23 pair.
// u2 = u1 + red(P1); final logit from E2-half; output from E3-half; uout direct.
__global__ __launch_bounds__(1024) void hop2_final(const unsigned* __restrict__ E23,
                                                   const float* __restrict__ u1,
                                                   const float* __restrict__ P1,
                                                   float* __restrict__ logit,
                                                   float* __restrict__ uout) {
    const int b = blockIdx.x;
    const int tid = threadIdx.x;
    const int w = tid >> 6, lane = tid & 63;
    __shared__ float su[DD];
    __shared__ float sx[16][64], sy[16][64];
    __shared__ float sd[16];

    if (tid < DD) {
        float num = 0.f, dsum = 0.f;
        for (int cc = 0; cc < NCHUNK; ++cc) {
            const float* p = P1 + ((size_t)b * NCHUNK + cc) * PSTRIDE;
            num += p[tid];
            dsum += p[DD];
        }
        su[tid] = u1[b * DD + tid] + num / dsum;
    }
    __syncthreads();
    const float2 uv = ((const float2*)su)[lane];

    float nx = 0.f, ny = 0.f, den = 0.f;
#pragma unroll 4
    for (int m = w * 32; m < w * 32 + 32; ++m) {
        const int bm = b * MM + m;
        const uint2 q = ((const uint2*)E23)[(size_t)bm * 64 + lane];
        float l = bflo(q.x) * uv.x + bfhi(q.x) * uv.y;
#pragma unroll
        for (int off = 32; off; off >>= 1) l += __shfl_xor(l, off, 64);
        if (lane == 0) logit[bm] = l;
        const float e = expf(l);
        nx += e * bflo(q.y); ny += e * bfhi(q.y); den += e;
    }

    sx[w][lane] = nx; sy[w][lane] = ny;
    if (lane == 0) sd[w] = den;
    __syncthreads();
    if (w == 0) {
        float ox = 0.f, oy = 0.f, od = 0.f;
#pragma unroll
        for (int i = 0; i < 16; ++i) { ox += sx[i][lane]; oy += sy[i][lane]; od += sd[i]; }
        const float2 u2 = ((const float2*)su)[lane];
        ((float2*)(uout + b * DD))[lane] = make_float2(u2.x + ox / od, u2.y + oy / od);
    }
}

// ====================== FALLBACK PATH (round-1, known-good) ======================
__global__ __launch_bounds__(256) void init_u(const float* __restrict__ hidden,
                                              float* __restrict__ u) {
    int i = blockIdx.x * 256 + threadIdx.x;
    if (i < BB * DD) u[i] = hidden[i];
}

__global__ __launch_bounds__(256) void logit_kernel(const int* __restrict__ story,
                                                    const float* __restrict__ Ch,
                                                    const float* __restrict__ u,
                                                    float* __restrict__ logit) {
    int wid = (blockIdx.x * 256 + threadIdx.x) >> 6;
    int lane = threadIdx.x & 63;
    if (wid >= BB * MM) return;
    int b = wid >> 9;
    const int* st = story + (size_t)wid * SS;
    int tok[SS];
#pragma unroll
    for (int s = 0; s < SS; ++s) tok[s] = st[s];
    float ax = 0.f, ay = 0.f;
#pragma unroll
    for (int s = 0; s < SS; ++s) {
        const float2 v = ((const float2*)(Ch + (size_t)tok[s] * DD))[lane];
        ax += v.x; ay += v.y;
    }
    const float2 uv = ((const float2*)(u + b * DD))[lane];
    float p = ax * uv.x + ay * uv.y;
#pragma unroll
    for (int off = 32; off; off >>= 1) p += __shfl_down(p, off, 64);
    if (lane == 0) logit[wid] = p;
}

__global__ __launch_bounds__(256) void softmax_kernel(const float* __restrict__ logit,
                                                      float* __restrict__ prob) {
    int b = blockIdx.x;
    int t = threadIdx.x;
    __shared__ float red[8];
    float l0 = logit[b * MM + t];
    float l1 = logit[b * MM + 256 + t];
    float mx = fmaxf(l0, l1);
#pragma unroll
    for (int off = 32; off; off >>= 1) mx = fmaxf(mx, __shfl_xor(mx, off, 64));
    if ((t & 63) == 0) red[t >> 6] = mx;
    __syncthreads();
    mx = fmaxf(fmaxf(red[0], red[1]), fmaxf(red[2], red[3]));
    float e0 = expf(l0 - mx), e1 = expf(l1 - mx);
    float s = e0 + e1;
#pragma unroll
    for (int off = 32; off; off >>= 1) s += __shfl_xor(s, off, 64);
    if ((t & 63) == 0) red[4 + (t >> 6)] = s;
    __syncthreads();
    s = red[4] + red[5] + red[6] + red[7];
    float inv = 1.0f / s;
    prob[b * MM + t] = e0 * inv;
    prob[b * MM + 256 + t] = e1 * inv;
}

__global__ __launch_bounds__(256) void partial_kernel(const int* __restrict__ story,
                                                      const float* __restrict__ Ch1,
                                                      const float* __restrict__ prob,
                                                      float* __restrict__ partial,
                                                      int chunk) {
    int b = blockIdx.y, c = blockIdx.x;
    int w = threadIdx.x >> 6, lane = threadIdx.x & 63;
    int m0 = c * chunk;
    float ax = 0.f, ay = 0.f;
    for (int m = m0 + w; m < m0 + chunk; m += 4) {
        float pw = prob[b * MM + m];
        const int* st = story + (size_t)(b * MM + m) * SS;
        int tok[SS];
#pragma unroll
        for (int s = 0; s < SS; ++s) tok[s] = st[s];
        float sx = 0.f, sy = 0.f;
#pragma unroll
        for (int s = 0; s < SS; ++s) {
            const float2 v = ((const float2*)(Ch1 + (size_t)tok[s] * DD))[lane];
            sx += v.x; sy += v.y;
        }
        ax += pw * sx; ay += pw * sy;
    }
    __shared__ float redx[4][64];
    __shared__ float redy[4][64];
    redx[w][lane] = ax;
    redy[w][lane] = ay;
    __syncthreads();
    if (w == 0) {
        float ox = redx[0][lane] + redx[1][lane] + redx[2][lane] + redx[3][lane];
        float oy = redy[0][lane] + redy[1][lane] + redy[2][lane] + redy[3][lane];
        float2* dst = (float2*)(partial + ((size_t)b * gridDim.x + c) * DD);
        dst[lane] = make_float2(ox, oy);
    }
}

__global__ __launch_bounds__(256) void update_kernel(const float* __restrict__ partial,
                                                     float* __restrict__ u, int NC) {
    int i = blockIdx.x * 256 + threadIdx.x;
    if (i >= BB * DD) return;
    int b = i >> 7, d = i & 127;
    float s = 0.f;
    for (int c = 0; c < NC; ++c) s += partial[((size_t)b * NC + c) * DD + d];
    u[i] += s;
}

extern "C" void kernel_launch(void* const* d_in, const int* in_sizes, int n_in,
                              void* d_out, int out_size, void* d_ws, size_t ws_size,
                              hipStream_t stream) {
    const int*   story  = (const int*)d_in[0];
    const float* hidden = (const float*)d_in[1];
    const float* Cmat   = (const float*)d_in[2];

    float* out   = (float*)d_out;
    float* logit = out;              // final prob_logit [B,M]
    float* uout  = out + BB * MM;    // final u [B,D]

    // ws words: cu0 | Cb1 | Cb23 | E1 | E23 | P0 P1 | u1
    const size_t szCU  = (size_t)VV * BB;        // 1.024M f32
    const size_t szCb1 = (size_t)VV * 64;        // 2.048M words
    const size_t szCbp = (size_t)VV * 128;       // 4.096M words
    const size_t szE1  = (size_t)BM * 64;        // 1.048M words
    const size_t szE23 = (size_t)BM * 128;       // 2.097M words
    const size_t szP   = (size_t)BB * NCHUNK * PSTRIDE;
    const size_t need  = (szCU + szCb1 + szCbp + szE1 + szE23 + 2 * szP + BB * DD)
                         * sizeof(float);

    if (ws_size >= need) {
        float*    cu0  = (float*)d_ws;
        unsigned* Cb1  = (unsigned*)d_ws + szCU;
        unsigned* Cb23 = Cb1 + szCb1;
        unsigned* E1   = Cb23 + szCbp;
        unsigned* E23  = E1 + szE1;
        float*    P0   = (float*)(E23 + szE23);
        float*    P1   = P0 + szP;
        float*    u1   = P1 + szP;

        gemv0_k<<<VV / 64, 256, 0, stream>>>(Cmat, hidden, cu0, Cmat, Cb1);
        hop0_k<<<dim3(NCHUNK, BB), 256, 0, stream>>>(story, cu0, Cb1, E1, P0,
                                                     Cmat, Cb23);
        hop1_k<<<dim3(NCHUNK, BB), 256, 0, stream>>>(story, Cb23, E1, hidden,
                                                     P0, u1, E23, P1);
        hop2_final<<<BB, 1024, 0, stream>>>(E23, u1, P1, logit, uout);
    } else {
        float* prob = (float*)d_ws;
        int NC = 32;
        while (NC > 1 && (size_t)(BB * MM + BB * NC * DD) * 4 > ws_size) NC >>= 1;
        float* partial = prob + BB * MM;
        int chunk = MM / NC;

        init_u<<<(BB * DD + 255) / 256, 256, 0, stream>>>(hidden, uout);
        for (int h = 0; h < HOPS; ++h) {
            const float* Ca = Cmat + (size_t)h * VV * DD;
            const float* Cc = Cmat + (size_t)(h + 1) * VV * DD;
            logit_kernel<<<(BB * MM) / 4, 256, 0, stream>>>(story, Ca, uout, logit);
            softmax_kernel<<<BB, 256, 0, stream>>>(logit, prob);
            partial_kernel<<<dim3(NC, BB), 256, 0, stream>>>(story, Cc, prob, partial, chunk);
            update_kernel<<<(BB * DD + 255) / 256, 256, 0, stream>>>(partial, uout, NC);
        }
    }
}

// Round 15
// 72.330 us; speedup vs baseline: 1.5737x; 1.2839x over previous
//
#include <hip/hip_runtime.h>

#define BB 32
#define MM 512
#define SS 10
#define VV 32000
#define DD 128
#define HOPS 3
#define BM (BB * MM)
#define NCHUNK 32          // chunks per b -> grid 32*32 = 1024 blocks for hop0/hop1
#define CHM (MM / NCHUNK)  // 16 m per chunk -> 4 m per wave
#define PSTRIDE 132        // partial row: 128 num + 1 den + pad
#define UTP ((size_t)VV * 32)   // uint4 cvt units per interleaved table-pair

// bf16 helpers (RN pack; exact unpack)
__device__ __forceinline__ unsigned bfrn(float f) {
    unsigned u = __float_as_uint(f);
    return (u + 0x7FFFu + ((u >> 16) & 1u)) >> 16;
}
__device__ __forceinline__ unsigned pk(float a, float b) { return bfrn(a) | (bfrn(b) << 16); }
__device__ __forceinline__ float bflo(unsigned q) { return __uint_as_float(q << 16); }
__device__ __forceinline__ float bfhi(unsigned q) { return __uint_as_float(q & 0xFFFF0000u); }

// pair cvt: row v = 128 words; uint2 word-pair for lane l = {tabA d=2l..2l+1, tabB d=2l..2l+1}
__device__ __forceinline__ void cvt_pair_unit(const float* __restrict__ CA,
                                              const float* __restrict__ CB,
                                              unsigned* __restrict__ dst, size_t g) {
    const size_t v = g >> 5, j = g & 31;
    const float4 a = ((const float4*)CA)[v * 32 + j];
    const float4 b = ((const float4*)CB)[v * 32 + j];
    uint4 o;
    o.x = pk(a.x, a.y);
    o.y = pk(b.x, b.y);
    o.z = pk(a.z, a.w);
    o.w = pk(b.z, b.w);
    ((uint4*)dst)[v * 32 + j] = o;
}

// ====================== PRIMARY PATH (4 kernels, all-validated pieces) ======================

// K0: build Cb01 (tables 0,1 interleaved bf16). 4000 blocks x 256, 1 unit/thread.
__global__ __launch_bounds__(256) void cvt01(const float* __restrict__ Cmat,
                                             unsigned* __restrict__ Cb01) {
    const size_t g = (size_t)blockIdx.x * 256 + threadIdx.x;
    if (g < UTP)
        cvt_pair_unit(Cmat, Cmat + (size_t)VV * DD, Cb01, g);
}

__device__ __forceinline__ void write_partial(const int b, const int c,
                                              const int w, const int lane,
                                              float nx, float ny, float den,
                                              float* __restrict__ pout,
                                              float (*sx)[64], float (*sy)[64],
                                              float* sd) {
    sx[w][lane] = nx; sy[w][lane] = ny;
    if (lane == 0) sd[w] = den;
    __syncthreads();
    if (w == 0) {
        const float ox = sx[0][lane] + sx[1][lane] + sx[2][lane] + sx[3][lane];
        const float oy = sy[0][lane] + sy[1][lane] + sy[2][lane] + sy[3][lane];
        float* prow = pout + ((size_t)b * NCHUNK + c) * PSTRIDE;
        ((float2*)prow)[lane] = make_float2(ox, oy);
        if (lane == 0) prow[DD] = sd[0] + sd[1] + sd[2] + sd[3];
    }
}

// K1 (hop0): one uint2 gather/token from Cb01 -> logit (C0 half) + E1/out (C1 half,
// E1 stored bf16-packed). Tail: cvt (C2,C3) -> Cb23 pair.
__global__ __launch_bounds__(256) void hop0_k(const int* __restrict__ story,
                                              const unsigned* __restrict__ Cb01,
                                              const float* __restrict__ hidden,
                                              unsigned* __restrict__ E1,
                                              float* __restrict__ P0,
                                              const float* __restrict__ Cmat,
                                              unsigned* __restrict__ Cb23) {
    const int b = blockIdx.y, c = blockIdx.x;
    const int tid = threadIdx.x;
    const int w = tid >> 6, lane = tid & 63;
    __shared__ float su[DD];
    __shared__ float sx[4][64], sy[4][64];
    __shared__ float sd[4];

    if (tid < DD) su[tid] = hidden[b * DD + tid];
    __syncthreads();
    const float2 uv = ((const float2*)su)[lane];
    const uint2* G = (const uint2*)Cb01;

    float nx = 0.f, ny = 0.f, den = 0.f;
#pragma unroll
    for (int k = 0; k < CHM / 4; ++k) {
        const int m = c * CHM + k * 4 + w;
        const int bm = b * MM + m;
        int tok[SS];
        const int* st = story + (size_t)bm * SS;
#pragma unroll
        for (int s = 0; s < SS; ++s) tok[s] = st[s];

        float ex = 0.f, ey = 0.f, rx = 0.f, ry = 0.f;
#pragma unroll
        for (int s = 0; s < SS; ++s) {
            const uint2 q = G[(size_t)tok[s] * 64 + lane];
            ex += bflo(q.x); ey += bfhi(q.x);
            rx += bflo(q.y); ry += bfhi(q.y);
        }
        float l = ex * uv.x + ey * uv.y;
#pragma unroll
        for (int off = 32; off; off >>= 1) l += __shfl_xor(l, off, 64);
        const float e = expf(l);

        E1[(size_t)bm * 64 + lane] = pk(rx, ry);
        nx += e * rx; ny += e * ry; den += e;
    }
    write_partial(b, c, w, lane, nx, ny, den, P0, sx, sy, sd);

    // cvt pair tail: 1024 blocks x 256 thr x 4 units = 1048576 >= UTP
    const size_t t0 = (((size_t)blockIdx.y * gridDim.x + blockIdx.x) * 256 + tid) * 4;
#pragma unroll
    for (int i = 0; i < 4; ++i) {
        const size_t g = t0 + i;
        if (g < UTP)
            cvt_pair_unit(Cmat + (size_t)2 * VV * DD, Cmat + (size_t)3 * VV * DD,
                          Cb23, g);
    }
}

// K2 (hop1): logit from E1 (bf16); one uint2 gather/token from Cb23 -> E23 (bf16 pair)
// + weighted acc (C2 half) -> P1. u1 = hidden + red(P0); c==0 materializes u1.
__global__ __launch_bounds__(256) void hop1_k(const int* __restrict__ story,
                                              const unsigned* __restrict__ Cb23,
                                              const unsigned* __restrict__ E1,
                                              const float* __restrict__ hidden,
                                              const float* __restrict__ P0,
                                              float* __restrict__ u1,
                                              unsigned* __restrict__ E23,
                                              float* __restrict__ P1) {
    const int b = blockIdx.y, c = blockIdx.x;
    const int tid = threadIdx.x;
    const int w = tid >> 6, lane = tid & 63;
    __shared__ float su[DD];
    __shared__ float sx[4][64], sy[4][64];
    __shared__ float sd[4];

    if (tid < DD) {
        float num = 0.f, dsum = 0.f;
        for (int cc = 0; cc < NCHUNK; ++cc) {
            const float* p = P0 + ((size_t)b * NCHUNK + cc) * PSTRIDE;
            num += p[tid];
            dsum += p[DD];
        }
        const float v = hidden[b * DD + tid] + num / dsum;
        if (c == 0) u1[b * DD + tid] = v;
        su[tid] = v;
    }
    __syncthreads();
    const float2 uv = ((const float2*)su)[lane];

    float nx = 0.f, ny = 0.f, den = 0.f;
#pragma unroll
    for (int k = 0; k < CHM / 4; ++k) {
        const int m = c * CHM + k * 4 + w;
        const int bm = b * MM + m;
        int tok[SS];
        const int* st = story + (size_t)bm * SS;
#pragma unroll
        for (int s = 0; s < SS; ++s) tok[s] = st[s];

        const unsigned eq = E1[(size_t)bm * 64 + lane];
        float l = bflo(eq) * uv.x + bfhi(eq) * uv.y;
#pragma unroll
        for (int off = 32; off; off >>= 1) l += __shfl_xor(l, off, 64);
        const float e = expf(l);

        float r2x = 0.f, r2y = 0.f, r3x = 0.f, r3y = 0.f;
#pragma unroll
        for (int s = 0; s < SS; ++s) {
            const uint2 q = ((const uint2*)Cb23)[(size_t)tok[s] * 64 + lane];
            r2x += bflo(q.x); r2y += bfhi(q.x);
            r3x += bflo(q.y); r3y += bfhi(q.y);
        }
        ((uint2*)E23)[(size_t)bm * 64 + lane] = make_uint2(pk(r2x, r2y), pk(r3x, r3y));
        nx += e * r2x; ny += e * r2y; den += e;
    }
    write_partial(b, c, w, lane, nx, ny, den, P1, sx, sy, sd);
}

// K3 (hop2 + final): one block per b, 1024 threads. Fully dense from E23 pair.
// u2 = u1 + red(P1); final logit from E2 half; output from E3 half; uout direct.
__global__ __launch_bounds__(1024) void hop2_final(const unsigned* __restrict__ E23,
                                                   const float* __restrict__ u1,
                                                   const float* __restrict__ P1,
                                                   float* __restrict__ logit,
                                                   float* __restrict__ uout) {
    const int b = blockIdx.x;
    const int tid = threadIdx.x;
    const int w = tid >> 6, lane = tid & 63;
    __shared__ float su[DD];
    __shared__ float sx[16][64], sy[16][64];
    __shared__ float sd[16];

    if (tid < DD) {
        float num = 0.f, dsum = 0.f;
        for (int cc = 0; cc < NCHUNK; ++cc) {
            const float* p = P1 + ((size_t)b * NCHUNK + cc) * PSTRIDE;
            num += p[tid];
            dsum += p[DD];
        }
        su[tid] = u1[b * DD + tid] + num / dsum;
    }
    __syncthreads();
    const float2 uv = ((const float2*)su)[lane];

    float nx = 0.f, ny = 0.f, den = 0.f;
#pragma unroll 4
    for (int m = w * 32; m < w * 32 + 32; ++m) {
        const int bm = b * MM + m;
        const uint2 q = ((const uint2*)E23)[(size_t)bm * 64 + lane];
        float l = bflo(q.x) * uv.x + bfhi(q.x) * uv.y;
#pragma unroll
        for (int off = 32; off; off >>= 1) l += __shfl_xor(l, off, 64);
        if (lane == 0) logit[bm] = l;
        const float e = expf(l);
        nx += e * bflo(q.y); ny += e * bfhi(q.y); den += e;
    }

    sx[w][lane] = nx; sy[w][lane] = ny;
    if (lane == 0) sd[w] = den;
    __syncthreads();
    if (w == 0) {
        float ox = 0.f, oy = 0.f, od = 0.f;
#pragma unroll
        for (int i = 0; i < 16; ++i) { ox += sx[i][lane]; oy += sy[i][lane]; od += sd[i]; }
        const float2 u2 = ((const float2*)su)[lane];
        ((float2*)(uout + b * DD))[lane] = make_float2(u2.x + ox / od, u2.y + oy / od);
    }
}

// ====================== FALLBACK PATH (round-1, known-good) ======================
__global__ __launch_bounds__(256) void init_u(const float* __restrict__ hidden,
                                              float* __restrict__ u) {
    int i = blockIdx.x * 256 + threadIdx.x;
    if (i < BB * DD) u[i] = hidden[i];
}

__global__ __launch_bounds__(256) void logit_kernel(const int* __restrict__ story,
                                                    const float* __restrict__ Ch,
                                                    const float* __restrict__ u,
                                                    float* __restrict__ logit) {
    int wid = (blockIdx.x * 256 + threadIdx.x) >> 6;
    int lane = threadIdx.x & 63;
    if (wid >= BB * MM) return;
    int b = wid >> 9;
    const int* st = story + (size_t)wid * SS;
    int tok[SS];
#pragma unroll
    for (int s = 0; s < SS; ++s) tok[s] = st[s];
    float ax = 0.f, ay = 0.f;
#pragma unroll
    for (int s = 0; s < SS; ++s) {
        const float2 v = ((const float2*)(Ch + (size_t)tok[s] * DD))[lane];
        ax += v.x; ay += v.y;
    }
    const float2 uv = ((const float2*)(u + b * DD))[lane];
    float p = ax * uv.x + ay * uv.y;
#pragma unroll
    for (int off = 32; off; off >>= 1) p += __shfl_down(p, off, 64);
    if (lane == 0) logit[wid] = p;
}

__global__ __launch_bounds__(256) void softmax_kernel(const float* __restrict__ logit,
                                                      float* __restrict__ prob) {
    int b = blockIdx.x;
    int t = threadIdx.x;
    __shared__ float red[8];
    float l0 = logit[b * MM + t];
    float l1 = logit[b * MM + 256 + t];
    float mx = fmaxf(l0, l1);
#pragma unroll
    for (int off = 32; off; off >>= 1) mx = fmaxf(mx, __shfl_xor(mx, off, 64));
    if ((t & 63) == 0) red[t >> 6] = mx;
    __syncthreads();
    mx = fmaxf(fmaxf(red[0], red[1]), fmaxf(red[2], red[3]));
    float e0 = expf(l0 - mx), e1 = expf(l1 - mx);
    float s = e0 + e1;
#pragma unroll
    for (int off = 32; off; off >>= 1) s += __shfl_xor(s, off, 64);
    if ((t & 63) == 0) red[4 + (t >> 6)] = s;
    __syncthreads();
    s = red[4] + red[5] + red[6] + red[7];
    float inv = 1.0f / s;
    prob[b * MM + t] = e0 * inv;
    prob[b * MM + 256 + t] = e1 * inv;
}

__global__ __launch_bounds__(256) void partial_kernel(const int* __restrict__ story,
                                                      const float* __restrict__ Ch1,
                                                      const float* __restrict__ prob,
                                                      float* __restrict__ partial,
                                                      int chunk) {
    int b = blockIdx.y, c = blockIdx.x;
    int w = threadIdx.x >> 6, lane = threadIdx.x & 63;
    int m0 = c * chunk;
    float ax = 0.f, ay = 0.f;
    for (int m = m0 + w; m < m0 + chunk; m += 4) {
        float pw = prob[b * MM + m];
        const int* st = story + (size_t)(b * MM + m) * SS;
        int tok[SS];
#pragma unroll
        for (int s = 0; s < SS; ++s) tok[s] = st[s];
        float sx = 0.f, sy = 0.f;
#pragma unroll
        for (int s = 0; s < SS; ++s) {
            const float2 v = ((const float2*)(Ch1 + (size_t)tok[s] * DD))[lane];
            sx += v.x; sy += v.y;
        }
        ax += pw * sx; ay += pw * sy;
    }
    __shared__ float redx[4][64];
    __shared__ float redy[4][64];
    redx[w][lane] = ax;
    redy[w][lane] = ay;
    __syncthreads();
    if (w == 0) {
        float ox = redx[0][lane] + redx[1][lane] + redx[2][lane] + redx[3][lane];
        float oy = redy[0][lane] + redy[1][lane] + redy[2][lane] + redy[3][lane];
        float2* dst = (float2*)(partial + ((size_t)b * gridDim.x + c) * DD);
        dst[lane] = make_float2(ox, oy);
    }
}

__global__ __launch_bounds__(256) void update_kernel(const float* __restrict__ partial,
                                                     float* __restrict__ u, int NC) {
    int i = blockIdx.x * 256 + threadIdx.x;
    if (i >= BB * DD) return;
    int b = i >> 7, d = i & 127;
    float s = 0.f;
    for (int c = 0; c < NC; ++c) s += partial[((size_t)b * NC + c) * DD + d];
    u[i] += s;
}

extern "C" void kernel_launch(void* const* d_in, const int* in_sizes, int n_in,
                              void* d_out, int out_size, void* d_ws, size_t ws_size,
                              hipStream_t stream) {
    const int*   story  = (const int*)d_in[0];
    const float* hidden = (const float*)d_in[1];
    const float* Cmat   = (const float*)d_in[2];

    float* out   = (float*)d_out;
    float* logit = out;              // final prob_logit [B,M]
    float* uout  = out + BB * MM;    // final u [B,D]

    // ws words: Cb01 | Cb23 | E1 | E23 | P0 P1 | u1
    const size_t szCbp = (size_t)VV * 128;       // words per interleaved bf16 pair
    const size_t szE1  = (size_t)BM * 64;        // bf16-packed E1
    const size_t szE23 = (size_t)BM * 128;       // bf16-packed E2,E3 pair
    const size_t szP   = (size_t)BB * NCHUNK * PSTRIDE;
    const size_t need  = (2 * szCbp + szE1 + szE23 + 2 * szP + BB * DD) * sizeof(float);

    if (ws_size >= need) {
        unsigned* Cb01 = (unsigned*)d_ws;
        unsigned* Cb23 = Cb01 + szCbp;
        unsigned* E1   = Cb23 + szCbp;
        unsigned* E23  = E1 + szE1;
        float*    P0   = (float*)(E23 + szE23);
        float*    P1   = P0 + szP;
        float*    u1   = P1 + szP;

        cvt01<<<(unsigned)((UTP + 255) / 256), 256, 0, stream>>>(Cmat, Cb01);
        hop0_k<<<dim3(NCHUNK, BB), 256, 0, stream>>>(story, Cb01, hidden, E1, P0,
                                                     Cmat, Cb23);
        hop1_k<<<dim3(NCHUNK, BB), 256, 0, stream>>>(story, Cb23, E1, hidden,
                                                     P0, u1, E23, P1);
        hop2_final<<<BB, 1024, 0, stream>>>(E23, u1, P1, logit, uout);
    } else {
        float* prob = (float*)d_ws;
        int NC = 32;
        while (NC > 1 && (size_t)(BB * MM + BB * NC * DD) * 4 > ws_size) NC >>= 1;
        float* partial = prob + BB * MM;
        int chunk = MM / NC;

        init_u<<<(BB * DD + 255) / 256, 256, 0, stream>>>(hidden, uout);
        for (int h = 0; h < HOPS; ++h) {
            const float* Ca = Cmat + (size_t)h * VV * DD;
            const float* Cc = Cmat + (size_t)(h + 1) * VV * DD;
            logit_kernel<<<(BB * MM) / 4, 256, 0, stream>>>(story, Ca, uout, logit);
            softmax_kernel<<<BB, 256, 0, stream>>>(logit, prob);
            partial_kernel<<<dim3(NC, BB), 256, 0, stream>>>(story, Cc, prob, partial, chunk);
            update_kernel<<<(BB * DD + 255) / 256, 256, 0, stream>>>(partial, uout, NC);
        }
    }
}

// Round 16
// 63.808 us; speedup vs baseline: 1.7839x; 1.1335x over previous
//
#include <hip/hip_runtime.h>

#define BB 32
#define MM 512
#define SS 10
#define VV 32000
#define DD 128
#define HOPS 3
#define BM (BB * MM)
#define NCHUNK 32          // chunks per b -> grid 32*32 = 1024 blocks per hop
#define CHM (MM / NCHUNK)  // 16 m per chunk -> 4 m per wave
#define PSTRIDE 132        // partial row: 128 num + 1 den + pad
#define UTP ((size_t)VV * 32)   // uint4 cvt units per interleaved table-pair

// bf16 helpers (RN pack; exact unpack)
__device__ __forceinline__ unsigned bfrn(float f) {
    unsigned u = __float_as_uint(f);
    return (u + 0x7FFFu + ((u >> 16) & 1u)) >> 16;
}
__device__ __forceinline__ unsigned pk(float a, float b) { return bfrn(a) | (bfrn(b) << 16); }
__device__ __forceinline__ float bflo(unsigned q) { return __uint_as_float(q << 16); }
__device__ __forceinline__ float bfhi(unsigned q) { return __uint_as_float(q & 0xFFFF0000u); }

// pair cvt: row v = 128 words; uint2 for lane l = {tabA d=2l..2l+1, tabB d=2l..2l+1}
__device__ __forceinline__ void cvt_pair_unit(const float* __restrict__ CA,
                                              const float* __restrict__ CB,
                                              unsigned* __restrict__ dst, size_t g) {
    const size_t v = g >> 5, j = g & 31;
    const float4 a = ((const float4*)CA)[v * 32 + j];
    const float4 b = ((const float4*)CB)[v * 32 + j];
    uint4 o;
    o.x = pk(a.x, a.y);
    o.y = pk(b.x, b.y);
    o.z = pk(a.z, a.w);
    o.w = pk(b.z, b.w);
    ((uint4*)dst)[v * 32 + j] = o;
}

// ====================== PRIMARY PATH (R11 structure, bf16 E) ======================

// K0: build Cb01 (tables 0,1 interleaved bf16). 4000 blocks x 256, 1 unit/thread.
__global__ __launch_bounds__(256) void cvt01(const float* __restrict__ Cmat,
                                             unsigned* __restrict__ Cb01) {
    const size_t g = (size_t)blockIdx.x * 256 + threadIdx.x;
    if (g < UTP)
        cvt_pair_unit(Cmat, Cmat + (size_t)VV * DD, Cb01, g);
}

__device__ __forceinline__ void write_partial(const int b, const int c,
                                              const int w, const int lane,
                                              float nx, float ny, float den,
                                              float* __restrict__ pout,
                                              float (*sx)[64], float (*sy)[64],
                                              float* sd) {
    sx[w][lane] = nx; sy[w][lane] = ny;
    if (lane == 0) sd[w] = den;
    __syncthreads();
    if (w == 0) {
        const float ox = sx[0][lane] + sx[1][lane] + sx[2][lane] + sx[3][lane];
        const float oy = sy[0][lane] + sy[1][lane] + sy[2][lane] + sy[3][lane];
        float* prow = pout + ((size_t)b * NCHUNK + c) * PSTRIDE;
        ((float2*)prow)[lane] = make_float2(ox, oy);
        if (lane == 0) prow[DD] = sd[0] + sd[1] + sd[2] + sd[3];
    }
}

// K1 (hop0): one uint2 gather/token from Cb01 -> logit (C0 half) + E1/out (C1 half,
// stored bf16-packed). Tail: cvt (C2,C3) -> Cb23 pair.
__global__ __launch_bounds__(256) void hop0_k(const int* __restrict__ story,
                                              const unsigned* __restrict__ Cb01,
                                              const float* __restrict__ hidden,
                                              unsigned* __restrict__ E1,
                                              float* __restrict__ P0,
                                              const float* __restrict__ Cmat,
                                              unsigned* __restrict__ Cb23) {
    const int b = blockIdx.y, c = blockIdx.x;
    const int tid = threadIdx.x;
    const int w = tid >> 6, lane = tid & 63;
    __shared__ float su[DD];
    __shared__ float sx[4][64], sy[4][64];
    __shared__ float sd[4];

    if (tid < DD) su[tid] = hidden[b * DD + tid];
    __syncthreads();
    const float2 uv = ((const float2*)su)[lane];
    const uint2* G = (const uint2*)Cb01;

    float nx = 0.f, ny = 0.f, den = 0.f;
#pragma unroll
    for (int k = 0; k < CHM / 4; ++k) {
        const int m = c * CHM + k * 4 + w;
        const int bm = b * MM + m;
        int tok[SS];
        const int* st = story + (size_t)bm * SS;
#pragma unroll
        for (int s = 0; s < SS; ++s) tok[s] = st[s];

        float ex = 0.f, ey = 0.f, rx = 0.f, ry = 0.f;
#pragma unroll
        for (int s = 0; s < SS; ++s) {
            const uint2 q = G[(size_t)tok[s] * 64 + lane];
            ex += bflo(q.x); ey += bfhi(q.x);
            rx += bflo(q.y); ry += bfhi(q.y);
        }
        float l = ex * uv.x + ey * uv.y;
#pragma unroll
        for (int off = 32; off; off >>= 1) l += __shfl_xor(l, off, 64);
        const float e = expf(l);

        E1[(size_t)bm * 64 + lane] = pk(rx, ry);
        nx += e * rx; ny += e * ry; den += e;
    }
    write_partial(b, c, w, lane, nx, ny, den, P0, sx, sy, sd);

    // cvt pair tail: 1024 blocks x 256 thr x 4 units = 1048576 >= UTP
    const size_t t0 = (((size_t)blockIdx.y * gridDim.x + blockIdx.x) * 256 + tid) * 4;
#pragma unroll
    for (int i = 0; i < 4; ++i) {
        const size_t g = t0 + i;
        if (g < UTP)
            cvt_pair_unit(Cmat + (size_t)2 * VV * DD, Cmat + (size_t)3 * VV * DD,
                          Cb23, g);
    }
}

// K2 (hop1): logit from E1 (bf16); one uint2 gather/token from Cb23 -> E23 (bf16 pair)
// + weighted acc (C2 half) -> P1. u1 = hidden + red(P0); c==0 materializes u1.
__global__ __launch_bounds__(256) void hop1_k(const int* __restrict__ story,
                                              const unsigned* __restrict__ Cb23,
                                              const unsigned* __restrict__ E1,
                                              const float* __restrict__ hidden,
                                              const float* __restrict__ P0,
                                              float* __restrict__ u1,
                                              unsigned* __restrict__ E23,
                                              float* __restrict__ P1) {
    const int b = blockIdx.y, c = blockIdx.x;
    const int tid = threadIdx.x;
    const int w = tid >> 6, lane = tid & 63;
    __shared__ float su[DD];
    __shared__ float sx[4][64], sy[4][64];
    __shared__ float sd[4];

    if (tid < DD) {
        float num = 0.f, dsum = 0.f;
        for (int cc = 0; cc < NCHUNK; ++cc) {
            const float* p = P0 + ((size_t)b * NCHUNK + cc) * PSTRIDE;
            num += p[tid];
            dsum += p[DD];
        }
        const float v = hidden[b * DD + tid] + num / dsum;
        if (c == 0) u1[b * DD + tid] = v;
        su[tid] = v;
    }
    __syncthreads();
    const float2 uv = ((const float2*)su)[lane];

    float nx = 0.f, ny = 0.f, den = 0.f;
#pragma unroll
    for (int k = 0; k < CHM / 4; ++k) {
        const int m = c * CHM + k * 4 + w;
        const int bm = b * MM + m;
        int tok[SS];
        const int* st = story + (size_t)bm * SS;
#pragma unroll
        for (int s = 0; s < SS; ++s) tok[s] = st[s];

        const unsigned eq = E1[(size_t)bm * 64 + lane];
        float l = bflo(eq) * uv.x + bfhi(eq) * uv.y;
#pragma unroll
        for (int off = 32; off; off >>= 1) l += __shfl_xor(l, off, 64);
        const float e = expf(l);

        float r2x = 0.f, r2y = 0.f, r3x = 0.f, r3y = 0.f;
#pragma unroll
        for (int s = 0; s < SS; ++s) {
            const uint2 q = ((const uint2*)Cb23)[(size_t)tok[s] * 64 + lane];
            r2x += bflo(q.x); r2y += bfhi(q.x);
            r3x += bflo(q.y); r3y += bfhi(q.y);
        }
        ((uint2*)E23)[(size_t)bm * 64 + lane] = make_uint2(pk(r2x, r2y), pk(r3x, r3y));
        nx += e * r2x; ny += e * r2y; den += e;
    }
    write_partial(b, c, w, lane, nx, ny, den, P1, sx, sy, sd);
}

// K3 (hop2): WIDE grid (NCHUNK x BB), reads E23 pair; logit from E2 half (writes
// final logit), output from E3 half -> P2. u2 = u1 + red(P1); c==0 materializes u2.
__global__ __launch_bounds__(256) void hop2_k(const unsigned* __restrict__ E23,
                                              const float* __restrict__ u1,
                                              const float* __restrict__ P1,
                                              float* __restrict__ u2,
                                              float* __restrict__ logit,
                                              float* __restrict__ P2) {
    const int b = blockIdx.y, c = blockIdx.x;
    const int tid = threadIdx.x;
    const int w = tid >> 6, lane = tid & 63;
    __shared__ float su[DD];
    __shared__ float sx[4][64], sy[4][64];
    __shared__ float sd[4];

    if (tid < DD) {
        float num = 0.f, dsum = 0.f;
        for (int cc = 0; cc < NCHUNK; ++cc) {
            const float* p = P1 + ((size_t)b * NCHUNK + cc) * PSTRIDE;
            num += p[tid];
            dsum += p[DD];
        }
        const float v = u1[b * DD + tid] + num / dsum;
        if (c == 0) u2[b * DD + tid] = v;
        su[tid] = v;
    }
    __syncthreads();
    const float2 uv = ((const float2*)su)[lane];

    float nx = 0.f, ny = 0.f, den = 0.f;
#pragma unroll
    for (int k = 0; k < CHM / 4; ++k) {
        const int m = c * CHM + k * 4 + w;
        const int bm = b * MM + m;
        const uint2 q = ((const uint2*)E23)[(size_t)bm * 64 + lane];
        float l = bflo(q.x) * uv.x + bfhi(q.x) * uv.y;
#pragma unroll
        for (int off = 32; off; off >>= 1) l += __shfl_xor(l, off, 64);
        if (lane == 0) logit[bm] = l;
        const float e = expf(l);
        nx += e * bflo(q.y); ny += e * bfhi(q.y); den += e;
    }
    write_partial(b, c, w, lane, nx, ny, den, P2, sx, sy, sd);
}

// K4 final: uout = u2 + red(P2)
__global__ __launch_bounds__(128) void final_u(const float* __restrict__ pin,
                                               const float* __restrict__ u2,
                                               float* __restrict__ uout) {
    const int b = blockIdx.x, d = threadIdx.x;
    float num = 0.f, den = 0.f;
    for (int cc = 0; cc < NCHUNK; ++cc) {
        const float* p = pin + ((size_t)b * NCHUNK + cc) * PSTRIDE;
        num += p[d];
        den += p[DD];
    }
    uout[b * DD + d] = u2[b * DD + d] + num / den;
}

// ====================== FALLBACK PATH (round-1, known-good) ======================
__global__ __launch_bounds__(256) void init_u(const float* __restrict__ hidden,
                                              float* __restrict__ u) {
    int i = blockIdx.x * 256 + threadIdx.x;
    if (i < BB * DD) u[i] = hidden[i];
}

__global__ __launch_bounds__(256) void logit_kernel(const int* __restrict__ story,
                                                    const float* __restrict__ Ch,
                                                    const float* __restrict__ u,
                                                    float* __restrict__ logit) {
    int wid = (blockIdx.x * 256 + threadIdx.x) >> 6;
    int lane = threadIdx.x & 63;
    if (wid >= BB * MM) return;
    int b = wid >> 9;
    const int* st = story + (size_t)wid * SS;
    int tok[SS];
#pragma unroll
    for (int s = 0; s < SS; ++s) tok[s] = st[s];
    float ax = 0.f, ay = 0.f;
#pragma unroll
    for (int s = 0; s < SS; ++s) {
        const float2 v = ((const float2*)(Ch + (size_t)tok[s] * DD))[lane];
        ax += v.x; ay += v.y;
    }
    const float2 uv = ((const float2*)(u + b * DD))[lane];
    float p = ax * uv.x + ay * uv.y;
#pragma unroll
    for (int off = 32; off; off >>= 1) p += __shfl_down(p, off, 64);
    if (lane == 0) logit[wid] = p;
}

__global__ __launch_bounds__(256) void softmax_kernel(const float* __restrict__ logit,
                                                      float* __restrict__ prob) {
    int b = blockIdx.x;
    int t = threadIdx.x;
    __shared__ float red[8];
    float l0 = logit[b * MM + t];
    float l1 = logit[b * MM + 256 + t];
    float mx = fmaxf(l0, l1);
#pragma unroll
    for (int off = 32; off; off >>= 1) mx = fmaxf(mx, __shfl_xor(mx, off, 64));
    if ((t & 63) == 0) red[t >> 6] = mx;
    __syncthreads();
    mx = fmaxf(fmaxf(red[0], red[1]), fmaxf(red[2], red[3]));
    float e0 = expf(l0 - mx), e1 = expf(l1 - mx);
    float s = e0 + e1;
#pragma unroll
    for (int off = 32; off; off >>= 1) s += __shfl_xor(s, off, 64);
    if ((t & 63) == 0) red[4 + (t >> 6)] = s;
    __syncthreads();
    s = red[4] + red[5] + red[6] + red[7];
    float inv = 1.0f / s;
    prob[b * MM + t] = e0 * inv;
    prob[b * MM + 256 + t] = e1 * inv;
}

__global__ __launch_bounds__(256) void partial_kernel(const int* __restrict__ story,
                                                      const float* __restrict__ Ch1,
                                                      const float* __restrict__ prob,
                                                      float* __restrict__ partial,
                                                      int chunk) {
    int b = blockIdx.y, c = blockIdx.x;
    int w = threadIdx.x >> 6, lane = threadIdx.x & 63;
    int m0 = c * chunk;
    float ax = 0.f, ay = 0.f;
    for (int m = m0 + w; m < m0 + chunk; m += 4) {
        float pw = prob[b * MM + m];
        const int* st = story + (size_t)(b * MM + m) * SS;
        int tok[SS];
#pragma unroll
        for (int s = 0; s < SS; ++s) tok[s] = st[s];
        float sx = 0.f, sy = 0.f;
#pragma unroll
        for (int s = 0; s < SS; ++s) {
            const float2 v = ((const float2*)(Ch1 + (size_t)tok[s] * DD))[lane];
            sx += v.x; sy += v.y;
        }
        ax += pw * sx; ay += pw * sy;
    }
    __shared__ float redx[4][64];
    __shared__ float redy[4][64];
    redx[w][lane] = ax;
    redy[w][lane] = ay;
    __syncthreads();
    if (w == 0) {
        float ox = redx[0][lane] + redx[1][lane] + redx[2][lane] + redx[3][lane];
        float oy = redy[0][lane] + redy[1][lane] + redy[2][lane] + redy[3][lane];
        float2* dst = (float2*)(partial + ((size_t)b * gridDim.x + c) * DD);
        dst[lane] = make_float2(ox, oy);
    }
}

__global__ __launch_bounds__(256) void update_kernel(const float* __restrict__ partial,
                                                     float* __restrict__ u, int NC) {
    int i = blockIdx.x * 256 + threadIdx.x;
    if (i >= BB * DD) return;
    int b = i >> 7, d = i & 127;
    float s = 0.f;
    for (int c = 0; c < NC; ++c) s += partial[((size_t)b * NC + c) * DD + d];
    u[i] += s;
}

extern "C" void kernel_launch(void* const* d_in, const int* in_sizes, int n_in,
                              void* d_out, int out_size, void* d_ws, size_t ws_size,
                              hipStream_t stream) {
    const int*   story  = (const int*)d_in[0];
    const float* hidden = (const float*)d_in[1];
    const float* Cmat   = (const float*)d_in[2];

    float* out   = (float*)d_out;
    float* logit = out;              // final prob_logit [B,M]
    float* uout  = out + BB * MM;    // final u [B,D]

    // ws words: Cb01 | Cb23 | E1 | E23 | Pa Pb Pc | u1 u2
    const size_t szCbp = (size_t)VV * 128;       // interleaved bf16 pair
    const size_t szE1  = (size_t)BM * 64;        // bf16-packed E1
    const size_t szE23 = (size_t)BM * 128;       // bf16-packed E2,E3 pair
    const size_t szP   = (size_t)BB * NCHUNK * PSTRIDE;
    const size_t need  = (2 * szCbp + szE1 + szE23 + 3 * szP + 2 * BB * DD)
                         * sizeof(float);

    if (ws_size >= need) {
        unsigned* Cb01 = (unsigned*)d_ws;
        unsigned* Cb23 = Cb01 + szCbp;
        unsigned* E1   = Cb23 + szCbp;
        unsigned* E23  = E1 + szE1;
        float*    P0   = (float*)(E23 + szE23);
        float*    P1   = P0 + szP;
        float*    P2   = P1 + szP;
        float*    u1   = P2 + szP;
        float*    u2   = u1 + BB * DD;

        cvt01<<<(unsigned)((UTP + 255) / 256), 256, 0, stream>>>(Cmat, Cb01);
        hop0_k<<<dim3(NCHUNK, BB), 256, 0, stream>>>(story, Cb01, hidden, E1, P0,
                                                     Cmat, Cb23);
        hop1_k<<<dim3(NCHUNK, BB), 256, 0, stream>>>(story, Cb23, E1, hidden,
                                                     P0, u1, E23, P1);
        hop2_k<<<dim3(NCHUNK, BB), 256, 0, stream>>>(E23, u1, P1, u2, logit, P2);
        final_u<<<BB, 128, 0, stream>>>(P2, u2, uout);
    } else {
        float* prob = (float*)d_ws;
        int NC = 32;
        while (NC > 1 && (size_t)(BB * MM + BB * NC * DD) * 4 > ws_size) NC >>= 1;
        float* partial = prob + BB * MM;
        int chunk = MM / NC;

        init_u<<<(BB * DD + 255) / 256, 256, 0, stream>>>(hidden, uout);
        for (int h = 0; h < HOPS; ++h) {
            const float* Ca = Cmat + (size_t)h * VV * DD;
            const float* Cc = Cmat + (size_t)(h + 1) * VV * DD;
            logit_kernel<<<(BB * MM) / 4, 256, 0, stream>>>(story, Ca, uout, logit);
            softmax_kernel<<<BB, 256, 0, stream>>>(logit, prob);
            partial_kernel<<<dim3(NC, BB), 256, 0, stream>>>(story, Cc, prob, partial, chunk);
            update_kernel<<<(BB * DD + 255) / 256, 256, 0, stream>>>(partial, uout, NC);
        }
    }
}